// Round 11
// baseline (139.046 us; speedup 1.0000x reference)
//
#include <hip/hip_runtime.h>
#include <cfloat>
#include <math.h>

// Problem constants (fixed by the reference)
#define B_ROWS   4096
#define DIM      512
#define NPROTO   1000
#define NPROTO_P 1024
#define NCLASSES 10000
#define KSEL     10
#define KCAND    12                // approx candidates rescored in f32
#define CAP      256               // bucket capacity (avg 41)

#define OUT_N4   10240000u         // 163,840,000 B / 16

typedef short s16x8 __attribute__((ext_vector_type(8)));
typedef float f32x4 __attribute__((ext_vector_type(4)));

static __device__ __forceinline__ unsigned short f2bf(float f) {
  unsigned int x = __float_as_uint(f);
  return (unsigned short)((x + 0x7fffu + ((x >> 16) & 1u)) >> 16);  // RNE
}
static __device__ __forceinline__ s16x8 cvt8(float4 a, float4 b) {
  s16x8 r;
  r[0]=f2bf(a.x); r[1]=f2bf(a.y); r[2]=f2bf(a.z); r[3]=f2bf(a.w);
  r[4]=f2bf(b.x); r[5]=f2bf(b.y); r[6]=f2bf(b.z); r[7]=f2bf(b.w);
  return r;
}
static __device__ __forceinline__ unsigned f2h(float f) {
  _Float16 h = (_Float16)f;
  return (unsigned)__builtin_bit_cast(unsigned short, h);
}
// monotone map: IEEE f16 bits -> u16 preserving order (no NaNs here)
static __device__ __forceinline__ unsigned mono16(unsigned h) {
  return (h & 0x8000u) ? (~h & 0xffffu) : (h | 0x8000u);
}

static __device__ __forceinline__ void zero_share(
    f32x4* __restrict__ z, unsigned start, unsigned count,
    unsigned gth, unsigned nthreads)
{
  const f32x4 z4 = (f32x4)0.f;
  for (unsigned i = start + gth; i < start + count; i += nthreads)
    __builtin_nontemporal_store(z4, z + i);
}

// ---------------------------------------------------------------------------
// Kernel 0: proto f32 -> bf16 (padded to 1024 rows) into d_ws; zero counts.
// ---------------------------------------------------------------------------
__global__ __launch_bounds__(256) void k_prep(
    const float* __restrict__ proto, short* __restrict__ protb,
    int* __restrict__ counts)
{
  const int u = blockIdx.x * 256 + threadIdx.x;    // 0..65535, 8 elems each
  s16x8 r = (s16x8)0;
  if (u * 8 < NPROTO * DIM) {
    const float4* s = reinterpret_cast<const float4*>(proto) + (size_t)u * 2;
    r = cvt8(s[0], s[1]);
  }
  *reinterpret_cast<s16x8*>(protb + (size_t)u * 8) = r;
  if (blockIdx.x == 0)
    for (int i = threadIdx.x; i < NPROTO; i += 256) counts[i] = 0;
}

// ---------------------------------------------------------------------------
// Kernel 1: FUSED gemm + top-12 + f32 rescore + top-10 + bucket build + zero.
// 256 blocks x 512 threads. Block b owns rows [b*16, b*16+16) x all 1024
// proto cols. Wave w covers cols [w*128, w*128+128) = 8 MFMA frags.
// A (img tile) in LDS bf16, k8-blocked; B (proto bf16) streamed global->reg
// (no barriers in K-loop). Epilogue: packed-u32 argmax per row (wave-local
// top-12 -> LDS pool -> cross-wave merge of 96 -> exact f32 rescore of 12 ->
// top-10 -> atomic bucket build). Then the single 164 MB output zero.
// ---------------------------------------------------------------------------
__global__ __launch_bounds__(512) void k_fused(
    const float* __restrict__ img, const float* __restrict__ proto,
    const short* __restrict__ protb, int* __restrict__ counts,
    int* __restrict__ buckets, f32x4* __restrict__ outz)
{
  __shared__ short A_lds[64 * 128];          // 16 rows x 512 k, k8-blocked (16 KB)
  __shared__ unsigned pool[16][8][KCAND];    // 6 KB

  const int tid  = threadIdx.x;
  const int wave = tid >> 6, lane = tid & 63;
  const int kg = lane >> 4, fr = lane & 15;
  const int row0 = blockIdx.x * 16;

  // ---- stage A: img 16x512 f32 -> bf16, layout [k>>3][row][k&7] ----
  {
    const int row = tid & 15, kc = tid >> 4;       // kc 0..31, 16 k-elems each
    const float4* s = reinterpret_cast<const float4*>(
        img + (size_t)(row0 + row) * DIM + kc * 16);
    float4 v0 = s[0], v1 = s[1], v2 = s[2], v3 = s[3];
    *(s16x8*)&A_lds[(kc * 2    ) * 128 + row * 8] = cvt8(v0, v1);
    *(s16x8*)&A_lds[(kc * 2 + 1) * 128 + row * 8] = cvt8(v2, v3);
  }
  __syncthreads();

  // ---- K-loop: B direct from global (bf16), no barriers ----
  const short* pb = protb + (size_t)(wave * 128 + fr) * DIM + kg * 8;

  f32x4 acc[8];
#pragma unroll
  for (int f = 0; f < 8; ++f) acc[f] = (f32x4)0.f;

#pragma unroll
  for (int kt = 0; kt < DIM / 32; ++kt) {
    s16x8 bf[8];
#pragma unroll
    for (int f = 0; f < 8; ++f)
      bf[f] = *(const s16x8*)(pb + (size_t)f * 16 * DIM + kt * 32);
    const s16x8 af = *(const s16x8*)&A_lds[(kt * 4 + kg) * 128 + fr * 8];
#pragma unroll
    for (int f = 0; f < 8; ++f)
      acc[f] = __builtin_amdgcn_mfma_f32_16x16x32_bf16(af, bf[f], acc[f], 0, 0, 0);
  }

  // ---- wave-local top-12 per row (C/D: col = lane&15, row = kg*4+reg) ----
#pragma unroll
  for (int reg = 0; reg < 4; ++reg) {
    const int row = kg * 4 + reg;
    unsigned pv[8];
#pragma unroll
    for (int f = 0; f < 8; ++f) {
      const int col = wave * 128 + f * 16 + fr;
      pv[f] = (col < NPROTO)
            ? ((mono16(f2h(acc[f][reg])) << 16) | (0xffffu - col)) : 0u;
    }
    for (int kk = 0; kk < KCAND; ++kk) {
      unsigned best = pv[0];
#pragma unroll
      for (int f = 1; f < 8; ++f) best = max(best, pv[f]);
#pragma unroll
      for (int off = 1; off < 16; off <<= 1)
        best = max(best, (unsigned)__shfl_xor((int)best, off));
      if (fr == kk) pool[row][wave][kk] = best;
#pragma unroll
      for (int f = 0; f < 8; ++f)
        if (pv[f] == best) pv[f] = 0u;
    }
  }
  __syncthreads();

  // ---- merge 96 -> top-12 -> exact f32 rescore -> top-10 -> buckets ----
  // wave w handles rows 2w, 2w+1
  for (int rr = 0; rr < 2; ++rr) {
    const int r    = wave * 2 + rr;
    const int grow = row0 + r;
    const unsigned* pl = &pool[r][0][0];           // 96 contiguous u32
    unsigned c0 = pl[lane];
    unsigned c1 = (lane < 32) ? pl[64 + lane] : 0u;

    int ci[KCAND];
    for (int kk = 0; kk < KCAND; ++kk) {
      unsigned best = max(c0, c1);
#pragma unroll
      for (int off = 32; off; off >>= 1)
        best = max(best, (unsigned)__shfl_xor((int)best, off));
      ci[kk] = 0xffff - (int)(best & 0xffffu);
      if (c0 == best) c0 = 0u;
      if (c1 == best) c1 = 0u;
    }

    const float4* a4 = reinterpret_cast<const float4*>(img + (size_t)grow * DIM);
    const float4 a0 = a4[lane], a1 = a4[64 + lane];
    float dv[KCAND];
#pragma unroll
    for (int j = 0; j < KCAND; ++j) {
      const float4* p4 = reinterpret_cast<const float4*>(proto + (size_t)ci[j] * DIM);
      const float4 b0 = p4[lane], b1 = p4[64 + lane];
      float s = 0.f;
      s = fmaf(a0.x, b0.x, s); s = fmaf(a0.y, b0.y, s);
      s = fmaf(a0.z, b0.z, s); s = fmaf(a0.w, b0.w, s);
      s = fmaf(a1.x, b1.x, s); s = fmaf(a1.y, b1.y, s);
      s = fmaf(a1.z, b1.z, s); s = fmaf(a1.w, b1.w, s);
#pragma unroll
      for (int off = 32; off; off >>= 1) s += __shfl_xor(s, off);
      dv[j] = s;
    }

    unsigned picked = 0;
    for (int kk = 0; kk < KSEL; ++kk) {
      float bv = -FLT_MAX;
      int   bj = 0;
#pragma unroll
      for (int j = 0; j < KCAND; ++j)
        if (!((picked >> j) & 1u) && dv[j] > bv) { bv = dv[j]; bj = j; }
      picked |= 1u << bj;
      if (lane == kk) {
        const int pp  = ci[bj];
        const int pos = atomicAdd(&counts[pp], 1);
        if (pos < CAP) buckets[pp * CAP + pos] = grow;
      }
    }
  }

  // ---- the single dense zero of d_out (post-everything, async drain) ----
  zero_share(outz, 0, OUT_N4, blockIdx.x * 512 + tid, 256 * 512);
}

// ---------------------------------------------------------------------------
// Kernel 2: one block per proto; stage its 10 raw text rows in LDS + inverse
// norms (scale folded into dot epilogue); prefetched bucketed-row loop.
// ---------------------------------------------------------------------------
__global__ __launch_bounds__(256) void k_compute(
    const float* __restrict__ img, const float* __restrict__ text,
    const int* __restrict__ counts, const int* __restrict__ buckets,
    const float* __restrict__ logit_scale, float* __restrict__ out)
{
  __shared__ float stext[KSEL * DIM];   // 20 KB (raw)
  __shared__ float sfac[KSEL];

  const int p    = blockIdx.x;
  const int tid  = threadIdx.x;
  const int wave = tid >> 6, lane = tid & 63;

  {
    const float4* src = reinterpret_cast<const float4*>(text + (size_t)p * KSEL * DIM);
    float4* dst = reinterpret_cast<float4*>(stext);
#pragma unroll
    for (int i = 0; i < 5; ++i) dst[tid + i * 256] = src[tid + i * 256];
  }
  __syncthreads();

  const float scale = expf(logit_scale[0]);
#pragma unroll
  for (int j = wave; j < KSEL; j += 4) {
    const float4* t4 = reinterpret_cast<const float4*>(stext + j * DIM);
    float4 v0 = t4[lane], v1 = t4[64 + lane];
    float s = 0.f;
    s = fmaf(v0.x, v0.x, s); s = fmaf(v0.y, v0.y, s);
    s = fmaf(v0.z, v0.z, s); s = fmaf(v0.w, v0.w, s);
    s = fmaf(v1.x, v1.x, s); s = fmaf(v1.y, v1.y, s);
    s = fmaf(v1.z, v1.z, s); s = fmaf(v1.w, v1.w, s);
#pragma unroll
    for (int off = 32; off; off >>= 1) s += __shfl_down(s, off);
    if (lane == 0) sfac[j] = scale / sqrtf(s);
  }
  __syncthreads();

  const int n = min(counts[p], CAP);
  const float4* st4 = reinterpret_cast<const float4*>(stext);
  const int* bkt = buckets + p * CAP;

  int row = -1, nrow;
  float4 a0, a1, na0, na1;
  if (wave < n) {
    row = bkt[wave];
    const float4* a4 = reinterpret_cast<const float4*>(img + (size_t)row * DIM);
    a0 = a4[lane]; a1 = a4[64 + lane];
  }

  for (int i = wave; i < n; i += 4) {
    const int inext = i + 4;
    if (inext < n) {
      nrow = bkt[inext];
      const float4* a4 = reinterpret_cast<const float4*>(img + (size_t)nrow * DIM);
      na0 = a4[lane]; na1 = a4[64 + lane];
    }

    float acc[KSEL];
#pragma unroll
    for (int j = 0; j < KSEL; ++j) {
      const float4 b0 = st4[j * 128 + lane];
      const float4 b1 = st4[j * 128 + 64 + lane];
      float s = 0.f;
      s = fmaf(a0.x, b0.x, s); s = fmaf(a0.y, b0.y, s);
      s = fmaf(a0.z, b0.z, s); s = fmaf(a0.w, b0.w, s);
      s = fmaf(a1.x, b1.x, s); s = fmaf(a1.y, b1.y, s);
      s = fmaf(a1.z, b1.z, s); s = fmaf(a1.w, b1.w, s);
      acc[j] = s;
    }
#pragma unroll
    for (int j = 0; j < KSEL; ++j) {
#pragma unroll
      for (int off = 32; off; off >>= 1)
        acc[j] += __shfl_xor(acc[j], off);
    }
    float v = acc[0];
#pragma unroll
    for (int j = 1; j < KSEL; ++j) if (lane == j) v = acc[j];
    if (lane < KSEL)
      out[(size_t)row * NCLASSES + p * KSEL + lane] = v * sfac[lane];

    row = nrow; a0 = na0; a1 = na1;
  }
}

// ---------------------------------------------------------------------------
extern "C" void kernel_launch(void* const* d_in, const int* in_sizes, int n_in,
                              void* d_out, int out_size, void* d_ws, size_t ws_size,
                              hipStream_t stream) {
  const float* img    = (const float*)d_in[0];
  const float* proto  = (const float*)d_in[1];
  const float* text   = (const float*)d_in[2];
  const float* lscale = (const float*)d_in[3];

  float*  out  = (float*)d_out;
  f32x4*  outz = (f32x4*)d_out;

  // ws layout (~2.05 MB): counts @0, buckets @4096, proto_bf16 @1MB
  int*   counts  = (int*)d_ws;
  int*   buckets = (int*)((char*)d_ws + 4096);
  short* protb   = (short*)((char*)d_ws + 1048576);

  k_prep<<<256, 256, 0, stream>>>(proto, protb, counts);
  k_fused<<<256, 512, 0, stream>>>(img, proto, protb, counts, buckets, outz);
  k_compute<<<NPROTO, 256, 0, stream>>>(img, text, counts, buckets, lscale, out);
}

// Round 12
// 116.193 us; speedup vs baseline: 1.1967x; 1.1967x over previous
//
#include <hip/hip_runtime.h>
#include <cfloat>
#include <math.h>

// Problem constants (fixed by the reference)
#define B_ROWS   4096
#define DIM      512
#define NPROTO   1000
#define NCLASSES 10000
#define KSEL     10
#define KCAND    12                // candidates rescored in f32
#define NHALF    16                // 8 col-blocks x 2 waves = 64-col half-tiles
#define CAP      256               // bucket capacity (avg 41)

#define OUT_N4   10240000u         // 163,840,000 B / 16
#define ZQ1      6144000u          // ~98 MB zeroed by gemm
#define ZQ2      (OUT_N4 - ZQ1)    // ~65.5 MB zeroed by select

// MFMA GEMM tiling (R10-verified structure)
#define GBM 64
#define GBN 128
#define GBK 32
#define ALD 40                     // padded LDS row stride (bf16 elems)

typedef short s16x8 __attribute__((ext_vector_type(8)));
typedef float f32x4 __attribute__((ext_vector_type(4)));

static __device__ __forceinline__ unsigned short f2bf(float f) {
  unsigned int x = __float_as_uint(f);
  return (unsigned short)((x + 0x7fffu + ((x >> 16) & 1u)) >> 16);  // RNE
}
static __device__ __forceinline__ s16x8 cvt8(float4 a, float4 b) {
  s16x8 r;
  r[0]=f2bf(a.x); r[1]=f2bf(a.y); r[2]=f2bf(a.z); r[3]=f2bf(a.w);
  r[4]=f2bf(b.x); r[5]=f2bf(b.y); r[6]=f2bf(b.z); r[7]=f2bf(b.w);
  return r;
}
static __device__ __forceinline__ unsigned f2h(float f) {
  _Float16 h = (_Float16)f;
  return (unsigned)__builtin_bit_cast(unsigned short, h);
}
// monotone map: IEEE f16 bits -> u16 preserving order (no NaNs here)
static __device__ __forceinline__ unsigned mono16(unsigned h) {
  return (h & 0x8000u) ? (~h & 0xffffu) : (h | 0x8000u);
}

static __device__ __forceinline__ void zero_share(
    f32x4* __restrict__ z, unsigned start, unsigned count,
    unsigned gth, unsigned nthreads)
{
  const f32x4 z4 = (f32x4)0.f;
  for (unsigned i = start + gth; i < start + count; i += nthreads)
    __builtin_nontemporal_store(z4, z + i);
}

// ---------------------------------------------------------------------------
// Kernel 1: bf16 MFMA GEMM (R10 memory structure: f32 global loads, inline
// cvt at LDS store, coalesced). Epilogue: per-row packed-u32 top-12 over this
// wave's 64 cols -> cand[row][half][12]. No prob buffer. Block (0,0) zeroes
// counts; all blocks write their zhi zero share post-loop (async drain).
// ---------------------------------------------------------------------------
__global__ __launch_bounds__(256) void k_gemm(
    const float* __restrict__ img, const float* __restrict__ proto,
    unsigned* __restrict__ cand, f32x4* __restrict__ outz,
    int* __restrict__ counts)
{
  __shared__ short Al[GBM * ALD];   // 5 KB
  __shared__ short Bl[GBN * ALD];   // 10 KB

  const int tid  = threadIdx.x;
  const int lane = tid & 63, wave = tid >> 6;
  const int wr = wave >> 1, wc = wave & 1;
  const int row0 = blockIdx.x * GBM;
  const int col0 = blockIdx.y * GBN;
  const unsigned gth = (blockIdx.y * gridDim.x + blockIdx.x) * 256 + tid;

  const int sr = tid >> 2;          // staging row 0..63
  const int sc = (tid & 3) * 8;     // staging k-col 0,8,16,24

  int pa = col0 + sr;      if (pa > NPROTO - 1) pa = NPROTO - 1;
  int pb = col0 + 64 + sr; if (pb > NPROTO - 1) pb = NPROTO - 1;
  const float* gA  = img   + (size_t)(row0 + sr) * DIM + sc;
  const float* gB0 = proto + (size_t)pa * DIM + sc;
  const float* gB1 = proto + (size_t)pb * DIM + sc;

  float4 ra0  = *(const float4*)(gA);      float4 ra1  = *(const float4*)(gA + 4);
  float4 rb00 = *(const float4*)(gB0);     float4 rb01 = *(const float4*)(gB0 + 4);
  float4 rb10 = *(const float4*)(gB1);     float4 rb11 = *(const float4*)(gB1 + 4);

  f32x4 acc[2][4];
#pragma unroll
  for (int m = 0; m < 2; ++m)
#pragma unroll
    for (int n = 0; n < 4; ++n) acc[m][n] = (f32x4)0.f;

  const int kg = lane >> 4;   // k-group 0..3 (row-slice in epilogue)
  const int fr = lane & 15;   // fragment row/col

  for (int kt = 0; kt < DIM / GBK; ++kt) {
    *(s16x8*)&Al[sr * ALD + sc]        = cvt8(ra0, ra1);
    *(s16x8*)&Bl[sr * ALD + sc]        = cvt8(rb00, rb01);
    *(s16x8*)&Bl[(64 + sr) * ALD + sc] = cvt8(rb10, rb11);
    __syncthreads();

    if (kt + 1 < DIM / GBK) {
      const int k0 = (kt + 1) * GBK;
      ra0  = *(const float4*)(gA + k0);   ra1  = *(const float4*)(gA + k0 + 4);
      rb00 = *(const float4*)(gB0 + k0);  rb01 = *(const float4*)(gB0 + k0 + 4);
      rb10 = *(const float4*)(gB1 + k0);  rb11 = *(const float4*)(gB1 + k0 + 4);
    }

    s16x8 af[2], bf[4];
#pragma unroll
    for (int m = 0; m < 2; ++m)
      af[m] = *(const s16x8*)&Al[(wr * 32 + m * 16 + fr) * ALD + kg * 8];
#pragma unroll
    for (int n = 0; n < 4; ++n)
      bf[n] = *(const s16x8*)&Bl[(wc * 64 + n * 16 + fr) * ALD + kg * 8];
#pragma unroll
    for (int m = 0; m < 2; ++m)
#pragma unroll
      for (int n = 0; n < 4; ++n)
        acc[m][n] = __builtin_amdgcn_mfma_f32_16x16x32_bf16(
            af[m], bf[n], acc[m][n], 0, 0, 0);
    __syncthreads();
  }

  // ---- epilogue: per-row top-12 over this wave's 64 cols ----
  // C/D layout (m89/m91): col = col0 + wc*64 + n*16 + fr,
  //                       row = row0 + wr*32 + m*16 + kg*4 + reg.
  // The 16 lanes of a kg-group hold all 64 cols of each of its 8 rows.
  const int half = blockIdx.y * 2 + wc;       // 0..15
#pragma unroll
  for (int m = 0; m < 2; ++m)
#pragma unroll
    for (int reg = 0; reg < 4; ++reg) {
      const int grow = row0 + wr * 32 + m * 16 + kg * 4 + reg;
      unsigned pv[4];
#pragma unroll
      for (int n = 0; n < 4; ++n) {
        const int col = col0 + wc * 64 + n * 16 + fr;
        pv[n] = (col < NPROTO)
              ? ((mono16(f2h(acc[m][n][reg])) << 16) | (0xffffu - col)) : 0u;
      }
      unsigned* cp = cand + (size_t)grow * (NHALF * KCAND) + half * KCAND;
      for (int kk = 0; kk < KCAND; ++kk) {
        unsigned best = max(max(pv[0], pv[1]), max(pv[2], pv[3]));
#pragma unroll
        for (int off = 1; off < 16; off <<= 1)
          best = max(best, (unsigned)__shfl_xor((int)best, off));
        if (fr == kk) cp[kk] = best;
#pragma unroll
        for (int n = 0; n < 4; ++n)
          if (pv[n] == best) pv[n] = 0u;
      }
    }

  if (blockIdx.x == 0 && blockIdx.y == 0)
    for (int i = tid; i < NPROTO; i += 256) counts[i] = 0;

  // post-loop zero share: no barrier after -> fully async drain
  zero_share(outz, 0, ZQ1, gth, 512 * 256);
}

// ---------------------------------------------------------------------------
// Kernel 2: merge 192 candidates -> top-12 -> exact f32 rescore -> top-10 ->
// bucket build. One wave per row, register-only merge; + zhi zero share.
// ---------------------------------------------------------------------------
__global__ __launch_bounds__(256) void k_select(
    const unsigned* __restrict__ cand, const float* __restrict__ img,
    const float* __restrict__ proto, int* __restrict__ counts,
    int* __restrict__ buckets, f32x4* __restrict__ outz)
{
  const int tid  = threadIdx.x;
  const int wave = tid >> 6, lane = tid & 63;
  const int row  = blockIdx.x * 4 + wave;

  const unsigned* pl = cand + (size_t)row * (NHALF * KCAND);   // 192 u32
  unsigned c0 = pl[lane];
  unsigned c1 = pl[64 + lane];
  unsigned c2 = pl[128 + lane];

  int ci[KCAND];
  for (int kk = 0; kk < KCAND; ++kk) {
    unsigned best = max(c0, max(c1, c2));
#pragma unroll
    for (int off = 32; off; off >>= 1)
      best = max(best, (unsigned)__shfl_xor((int)best, off));
    ci[kk] = 0xffff - (int)(best & 0xffffu);
    if (c0 == best) c0 = 0u;
    if (c1 == best) c1 = 0u;
    if (c2 == best) c2 = 0u;
  }

  // exact f32 rescore of the 12 candidates
  const float4* a4 = reinterpret_cast<const float4*>(img + (size_t)row * DIM);
  const float4 a0 = a4[lane], a1 = a4[64 + lane];
  float dv[KCAND];
#pragma unroll
  for (int j = 0; j < KCAND; ++j) {
    const float4* p4 = reinterpret_cast<const float4*>(proto + (size_t)ci[j] * DIM);
    const float4 b0 = p4[lane], b1 = p4[64 + lane];
    float s = 0.f;
    s = fmaf(a0.x, b0.x, s); s = fmaf(a0.y, b0.y, s);
    s = fmaf(a0.z, b0.z, s); s = fmaf(a0.w, b0.w, s);
    s = fmaf(a1.x, b1.x, s); s = fmaf(a1.y, b1.y, s);
    s = fmaf(a1.z, b1.z, s); s = fmaf(a1.w, b1.w, s);
#pragma unroll
    for (int off = 32; off; off >>= 1) s += __shfl_xor(s, off);
    dv[j] = s;
  }

  // top-10 pick (uniform across lanes) + bucket build (lane kk does pick kk)
  unsigned picked = 0;
  for (int kk = 0; kk < KSEL; ++kk) {
    float bv = -FLT_MAX;
    int   bj = 0;
#pragma unroll
    for (int j = 0; j < KCAND; ++j)
      if (!((picked >> j) & 1u) && dv[j] > bv) { bv = dv[j]; bj = j; }
    picked |= 1u << bj;
    if (lane == kk) {
      const int pp  = ci[bj];
      const int pos = atomicAdd(&counts[pp], 1);
      if (pos < CAP) buckets[pp * CAP + pos] = row;
    }
  }

  zero_share(outz, ZQ1, ZQ2, blockIdx.x * 256 + tid, 1024 * 256);
}

// ---------------------------------------------------------------------------
// Kernel 3: one block per proto; stage its 10 raw text rows in LDS + inverse
// norms (scale folded into dot epilogue); prefetched bucketed-row loop.
// ---------------------------------------------------------------------------
__global__ __launch_bounds__(256) void k_compute(
    const float* __restrict__ img, const float* __restrict__ text,
    const int* __restrict__ counts, const int* __restrict__ buckets,
    const float* __restrict__ logit_scale, float* __restrict__ out)
{
  __shared__ float stext[KSEL * DIM];   // 20 KB (raw)
  __shared__ float sfac[KSEL];

  const int p    = blockIdx.x;
  const int tid  = threadIdx.x;
  const int wave = tid >> 6, lane = tid & 63;

  {
    const float4* src = reinterpret_cast<const float4*>(text + (size_t)p * KSEL * DIM);
    float4* dst = reinterpret_cast<float4*>(stext);
#pragma unroll
    for (int i = 0; i < 5; ++i) dst[tid + i * 256] = src[tid + i * 256];
  }
  __syncthreads();

  const float scale = expf(logit_scale[0]);
#pragma unroll
  for (int j = wave; j < KSEL; j += 4) {
    const float4* t4 = reinterpret_cast<const float4*>(stext + j * DIM);
    float4 v0 = t4[lane], v1 = t4[64 + lane];
    float s = 0.f;
    s = fmaf(v0.x, v0.x, s); s = fmaf(v0.y, v0.y, s);
    s = fmaf(v0.z, v0.z, s); s = fmaf(v0.w, v0.w, s);
    s = fmaf(v1.x, v1.x, s); s = fmaf(v1.y, v1.y, s);
    s = fmaf(v1.z, v1.z, s); s = fmaf(v1.w, v1.w, s);
#pragma unroll
    for (int off = 32; off; off >>= 1) s += __shfl_down(s, off);
    if (lane == 0) sfac[j] = scale / sqrtf(s);
  }
  __syncthreads();

  const int n = min(counts[p], CAP);
  const float4* st4 = reinterpret_cast<const float4*>(stext);
  const int* bkt = buckets + p * CAP;

  int row = -1, nrow;
  float4 a0, a1, na0, na1;
  if (wave < n) {
    row = bkt[wave];
    const float4* a4 = reinterpret_cast<const float4*>(img + (size_t)row * DIM);
    a0 = a4[lane]; a1 = a4[64 + lane];
  }

  for (int i = wave; i < n; i += 4) {
    const int inext = i + 4;
    if (inext < n) {
      nrow = bkt[inext];
      const float4* a4 = reinterpret_cast<const float4*>(img + (size_t)nrow * DIM);
      na0 = a4[lane]; na1 = a4[64 + lane];
    }

    float acc[KSEL];
#pragma unroll
    for (int j = 0; j < KSEL; ++j) {
      const float4 b0 = st4[j * 128 + lane];
      const float4 b1 = st4[j * 128 + 64 + lane];
      float s = 0.f;
      s = fmaf(a0.x, b0.x, s); s = fmaf(a0.y, b0.y, s);
      s = fmaf(a0.z, b0.z, s); s = fmaf(a0.w, b0.w, s);
      s = fmaf(a1.x, b1.x, s); s = fmaf(a1.y, b1.y, s);
      s = fmaf(a1.z, b1.z, s); s = fmaf(a1.w, b1.w, s);
      acc[j] = s;
    }
#pragma unroll
    for (int j = 0; j < KSEL; ++j) {
#pragma unroll
      for (int off = 32; off; off >>= 1)
        acc[j] += __shfl_xor(acc[j], off);
    }
    float v = acc[0];
#pragma unroll
    for (int j = 1; j < KSEL; ++j) if (lane == j) v = acc[j];
    if (lane < KSEL)
      out[(size_t)row * NCLASSES + p * KSEL + lane] = v * sfac[lane];

    row = nrow; a0 = na0; a1 = na1;
  }
}

// ---------------------------------------------------------------------------
extern "C" void kernel_launch(void* const* d_in, const int* in_sizes, int n_in,
                              void* d_out, int out_size, void* d_ws, size_t ws_size,
                              hipStream_t stream) {
  const float* img    = (const float*)d_in[0];
  const float* proto  = (const float*)d_in[1];
  const float* text   = (const float*)d_in[2];
  const float* lscale = (const float*)d_in[3];

  float*  out  = (float*)d_out;
  f32x4*  outz = (f32x4*)d_out;

  // ws layout (~4.2 MB): counts @0, buckets @4096, cand @ 4096 + 1MB
  int*      counts  = (int*)d_ws;
  int*      buckets = (int*)((char*)d_ws + 4096);
  unsigned* cand    = (unsigned*)((char*)d_ws + 4096 + 1048576);

  k_gemm<<<dim3(B_ROWS / GBM, 1024 / GBN), 256, 0, stream>>>(
      img, proto, cand, outz, counts);
  k_select<<<B_ROWS / 4, 256, 0, stream>>>(
      cand, img, proto, counts, buckets, outz);
  k_compute<<<NPROTO, 256, 0, stream>>>(img, text, counts, buckets, lscale, out);
}

// Round 13
// 103.973 us; speedup vs baseline: 1.3373x; 1.1175x over previous
//
#include <hip/hip_runtime.h>
#include <cfloat>
#include <math.h>

// Problem constants (fixed by the reference)
#define B_ROWS   4096
#define DIM      512
#define NPROTO   1000
#define NCLASSES 10000
#define KSEL     10
#define KCAND    12                // approx candidates rescored in f32
#define CAP      256               // bucket capacity (avg 41)
#define PROB_LD  1024

// d_out layout: prob f16 4096x1024 at [0, PROB_BYTES). k_select self-zeroes
// each prob row after consuming it; zhi = [PROB_BYTES, OUT) is zeroed in
// shares by k_gemm (post-loop) and k_select, always POST-compute NT stores
// with no barrier after (R6 lesson: barrier forces vmcnt(0) drain).
#define PROB_BYTES 8388608u
#define OUT_BYTES  163840000u
#define ZHI_N4     ((OUT_BYTES - PROB_BYTES) / 16)   // 9715712 f32x4
#define ZQ1        6000000u                          // 96 MB zeroed by gemm
#define ZS1        0u
#define ZQ2        (ZHI_N4 - ZQ1)                    // ~59.5 MB by select
#define ZS2        ZQ1

// MFMA GEMM tiling (R10-verified structure + 1-barrier double buffer)
#define GBM 64
#define GBN 128
#define GBK 32
#define ALD 40                     // padded LDS row stride (bf16 elems)

typedef short s16x8 __attribute__((ext_vector_type(8)));
typedef short s16x4 __attribute__((ext_vector_type(4)));
typedef float f32x4 __attribute__((ext_vector_type(4)));

static __device__ __forceinline__ unsigned short f2bf(float f) {
  unsigned int x = __float_as_uint(f);
  return (unsigned short)((x + 0x7fffu + ((x >> 16) & 1u)) >> 16);  // RNE
}
static __device__ __forceinline__ s16x8 cvt8(float4 a, float4 b) {
  s16x8 r;
  r[0]=f2bf(a.x); r[1]=f2bf(a.y); r[2]=f2bf(a.z); r[3]=f2bf(a.w);
  r[4]=f2bf(b.x); r[5]=f2bf(b.y); r[6]=f2bf(b.z); r[7]=f2bf(b.w);
  return r;
}
static __device__ __forceinline__ unsigned short f2h(float f) {
  _Float16 h = (_Float16)f;
  return __builtin_bit_cast(unsigned short, h);
}
static __device__ __forceinline__ float bf2f(short v) {
  return __uint_as_float(((unsigned)(unsigned short)v) << 16);
}
// monotone map: IEEE f16 bits -> u16 preserving order (no NaNs here)
static __device__ __forceinline__ unsigned mono16(unsigned h) {
  return (h & 0x8000u) ? (~h & 0xffffu) : (h | 0x8000u);
}

static __device__ __forceinline__ void zero_share(
    f32x4* __restrict__ z, unsigned start, unsigned count,
    unsigned gth, unsigned nthreads)
{
  const f32x4 z4 = (f32x4)0.f;
  for (unsigned i = start + gth; i < start + count; i += nthreads)
    __builtin_nontemporal_store(z4, z + i);
}

// ---------------------------------------------------------------------------
// Kernel 0: img f32 -> bf16 (imgb in ws); zero counts. imgb is read by both
// k_gemm (A operand) and k_compute (halves its scattered img re-reads).
// ---------------------------------------------------------------------------
__global__ __launch_bounds__(256) void k_prep(
    const float* __restrict__ img, short* __restrict__ imgb,
    int* __restrict__ counts)
{
  const int u = blockIdx.x * 256 + threadIdx.x;    // 262144 units of 8 elems
  const float4* s = reinterpret_cast<const float4*>(img) + (size_t)u * 2;
  *reinterpret_cast<s16x8*>(imgb + (size_t)u * 8) = cvt8(s[0], s[1]);
  if (blockIdx.x == 0)
    for (int i = threadIdx.x; i < NPROTO; i += 256) counts[i] = 0;
}

// ---------------------------------------------------------------------------
// Kernel 1: prob(f16) = imgb @ bf16(proto).T via 16x16x32 MFMA.
// A loaded bf16 directly; B converted at LDS-store. Double-buffered LDS with
// ONE barrier per K-iter (stores target buf[cur], reads buf[cur]; next iter's
// stores hit the other buffer -- disjoint, race-free). Post-loop zero share.
// ---------------------------------------------------------------------------
__global__ __launch_bounds__(256) void k_gemm(
    const short* __restrict__ imgb, const float* __restrict__ proto,
    unsigned short* __restrict__ prob, f32x4* __restrict__ outz)
{
  __shared__ short Al[2][GBM * ALD];   // 2 x 5 KB
  __shared__ short Bl[2][GBN * ALD];   // 2 x 10 KB

  const int tid  = threadIdx.x;
  const int lane = tid & 63, wave = tid >> 6;
  const int wr = wave >> 1, wc = wave & 1;
  const int row0 = blockIdx.x * GBM;
  const int col0 = blockIdx.y * GBN;
  const unsigned gth = (blockIdx.y * gridDim.x + blockIdx.x) * 256 + tid;

  const int sr = tid >> 2;          // staging row 0..63
  const int sc = (tid & 3) * 8;     // staging k-col 0,8,16,24

  int pa = col0 + sr;      if (pa > NPROTO - 1) pa = NPROTO - 1;
  int pb = col0 + 64 + sr; if (pb > NPROTO - 1) pb = NPROTO - 1;
  const short* gA  = imgb  + (size_t)(row0 + sr) * DIM + sc;
  const float* gB0 = proto + (size_t)pa * DIM + sc;
  const float* gB1 = proto + (size_t)pb * DIM + sc;

  s16x8  ra   = *(const s16x8*)(gA);
  float4 rb00 = *(const float4*)(gB0), rb01 = *(const float4*)(gB0 + 4);
  float4 rb10 = *(const float4*)(gB1), rb11 = *(const float4*)(gB1 + 4);

  f32x4 acc[2][4];
#pragma unroll
  for (int m = 0; m < 2; ++m)
#pragma unroll
    for (int n = 0; n < 4; ++n) acc[m][n] = (f32x4)0.f;

  const int kg = lane >> 4;   // k-group 0..3
  const int fr = lane & 15;   // fragment row/col

  for (int kt = 0; kt < DIM / GBK; ++kt) {
    const int cur = kt & 1;
    *(s16x8*)&Al[cur][sr * ALD + sc]        = ra;
    *(s16x8*)&Bl[cur][sr * ALD + sc]        = cvt8(rb00, rb01);
    *(s16x8*)&Bl[cur][(64 + sr) * ALD + sc] = cvt8(rb10, rb11);

    if (kt + 1 < DIM / GBK) {
      const int k0 = (kt + 1) * GBK;
      ra   = *(const s16x8*)(gA + k0);
      rb00 = *(const float4*)(gB0 + k0);  rb01 = *(const float4*)(gB0 + k0 + 4);
      rb10 = *(const float4*)(gB1 + k0);  rb11 = *(const float4*)(gB1 + k0 + 4);
    }
    __syncthreads();   // drains LDS stores; single barrier per iter

    s16x8 af[2], bf[4];
#pragma unroll
    for (int m = 0; m < 2; ++m)
      af[m] = *(const s16x8*)&Al[cur][(wr * 32 + m * 16 + fr) * ALD + kg * 8];
#pragma unroll
    for (int n = 0; n < 4; ++n)
      bf[n] = *(const s16x8*)&Bl[cur][(wc * 64 + n * 16 + fr) * ALD + kg * 8];
#pragma unroll
    for (int m = 0; m < 2; ++m)
#pragma unroll
      for (int n = 0; n < 4; ++n)
        acc[m][n] = __builtin_amdgcn_mfma_f32_16x16x32_bf16(
            af[m], bf[n], acc[m][n], 0, 0, 0);
  }

  // epilogue: C/D layout (m89/m91): col = lane&15, row = (lane>>4)*4 + reg
#pragma unroll
  for (int m = 0; m < 2; ++m)
#pragma unroll
    for (int n = 0; n < 4; ++n) {
      const int r = row0 + wr * 32 + m * 16 + (lane >> 4) * 4;
      const int c = col0 + wc * 64 + n * 16 + fr;
#pragma unroll
      for (int reg = 0; reg < 4; ++reg)
        prob[(size_t)(r + reg) * PROB_LD + c] = f2h(acc[m][n][reg]);
    }

  // post-loop zero share: no barrier after -> fully async drain
  zero_share(outz, ZS1, ZQ1, gth, 512 * 256);
}

// ---------------------------------------------------------------------------
// Kernel 2: fused top-12 -> f32 rescore -> top-10 pick -> bucket build.
// One wave per row, register-packed argmax (R10-verbatim, proven).
// ---------------------------------------------------------------------------
__global__ __launch_bounds__(256) void k_select(
    unsigned short* __restrict__ prob, const float* __restrict__ img,
    const float* __restrict__ proto, int* __restrict__ counts,
    int* __restrict__ buckets, f32x4* __restrict__ outz)
{
  const int tid  = threadIdx.x;
  const int wave = tid >> 6, lane = tid & 63;
  const int row  = blockIdx.x * 4 + wave;

  // lane l owns u32 words l*8 .. l*8+7 of the row = cols l*16 .. l*16+15
  unsigned cand[16];
  {
    const uint4* pu = reinterpret_cast<const uint4*>(
        prob + (size_t)row * PROB_LD) + lane * 2;
    const uint4 w0 = pu[0], w1 = pu[1];
    const unsigned w[8] = {w0.x, w0.y, w0.z, w0.w, w1.x, w1.y, w1.z, w1.w};
    const int cbase = lane * 16;
#pragma unroll
    for (int r = 0; r < 8; ++r) {
      const int c0 = cbase + r * 2;
      const unsigned lo = w[r] & 0xffffu, hi = w[r] >> 16;
      cand[r * 2]     = (c0     < NPROTO) ? ((mono16(lo) << 16) | (0xffffu - c0))       : 0u;
      cand[r * 2 + 1] = (c0 + 1 < NPROTO) ? ((mono16(hi) << 16) | (0xffffu - (c0 + 1))) : 0u;
    }
  }

  // 12 rounds of pure-VALU wave argmax
  int ci[KCAND];
#pragma unroll
  for (int kk = 0; kk < KCAND; ++kk) {
    unsigned best = cand[0];
#pragma unroll
    for (int r = 1; r < 16; ++r) best = max(best, cand[r]);
#pragma unroll
    for (int off = 32; off; off >>= 1)
      best = max(best, (unsigned)__shfl_xor((int)best, off));
    ci[kk] = 0xffff - (int)(best & 0xffffu);
#pragma unroll
    for (int r = 0; r < 16; ++r)
      if (cand[r] == best) cand[r] = 0u;
  }

  // self-zero the consumed f16 prob row (2 KB = 128 f32x4)
  {
    const f32x4 z4 = (f32x4)0.f;
    f32x4* prow = reinterpret_cast<f32x4*>(prob + (size_t)row * PROB_LD);
    __builtin_nontemporal_store(z4, prow + lane);
    __builtin_nontemporal_store(z4, prow + 64 + lane);
  }

  // exact f32 rescore of the 12 candidates
  const float4* a4 = reinterpret_cast<const float4*>(img + (size_t)row * DIM);
  const float4 a0 = a4[lane], a1 = a4[64 + lane];
  float dv[KCAND];
#pragma unroll
  for (int j = 0; j < KCAND; ++j) {
    const float4* p4 = reinterpret_cast<const float4*>(proto + (size_t)ci[j] * DIM);
    const float4 b0 = p4[lane], b1 = p4[64 + lane];
    float s = 0.f;
    s = fmaf(a0.x, b0.x, s); s = fmaf(a0.y, b0.y, s);
    s = fmaf(a0.z, b0.z, s); s = fmaf(a0.w, b0.w, s);
    s = fmaf(a1.x, b1.x, s); s = fmaf(a1.y, b1.y, s);
    s = fmaf(a1.z, b1.z, s); s = fmaf(a1.w, b1.w, s);
#pragma unroll
    for (int off = 32; off; off >>= 1) s += __shfl_xor(s, off);
    dv[j] = s;
  }

  // top-10 pick (uniform across lanes) + bucket build (lane kk does pick kk)
  unsigned picked = 0;
  for (int kk = 0; kk < KSEL; ++kk) {
    float bv = -FLT_MAX;
    int   bj = 0;
#pragma unroll
    for (int j = 0; j < KCAND; ++j)
      if (!((picked >> j) & 1u) && dv[j] > bv) { bv = dv[j]; bj = j; }
    picked |= 1u << bj;
    if (lane == kk) {
      const int pp  = ci[bj];
      const int pos = atomicAdd(&counts[pp], 1);
      if (pos < CAP) buckets[pp * CAP + pos] = row;
    }
  }

  zero_share(outz, ZS2, ZQ2, blockIdx.x * 256 + tid, 1024 * 256);
}

// ---------------------------------------------------------------------------
// Kernel 3: one block per proto; stage its 10 raw text rows in LDS + inverse
// norms (scale folded into dot epilogue). Bucketed rows read from imgb (bf16,
// half the scattered-read traffic); 1-deep software prefetch.
// ---------------------------------------------------------------------------
__global__ __launch_bounds__(256) void k_compute(
    const short* __restrict__ imgb, const float* __restrict__ text,
    const int* __restrict__ counts, const int* __restrict__ buckets,
    const float* __restrict__ logit_scale, float* __restrict__ out)
{
  __shared__ float stext[KSEL * DIM];   // 20 KB (raw)
  __shared__ float sfac[KSEL];

  const int p    = blockIdx.x;
  const int tid  = threadIdx.x;
  const int wave = tid >> 6, lane = tid & 63;

  {
    const float4* src = reinterpret_cast<const float4*>(text + (size_t)p * KSEL * DIM);
    float4* dst = reinterpret_cast<float4*>(stext);
#pragma unroll
    for (int i = 0; i < 5; ++i) dst[tid + i * 256] = src[tid + i * 256];
  }
  __syncthreads();

  const float scale = expf(logit_scale[0]);
#pragma unroll
  for (int j = wave; j < KSEL; j += 4) {
    const float4* t4 = reinterpret_cast<const float4*>(stext + j * DIM);
    float4 v0 = t4[lane], v1 = t4[64 + lane];
    float s = 0.f;
    s = fmaf(v0.x, v0.x, s); s = fmaf(v0.y, v0.y, s);
    s = fmaf(v0.z, v0.z, s); s = fmaf(v0.w, v0.w, s);
    s = fmaf(v1.x, v1.x, s); s = fmaf(v1.y, v1.y, s);
    s = fmaf(v1.z, v1.z, s); s = fmaf(v1.w, v1.w, s);
#pragma unroll
    for (int off = 32; off; off >>= 1) s += __shfl_down(s, off);
    if (lane == 0) sfac[j] = scale / sqrtf(s);
  }
  __syncthreads();

  const int n = min(counts[p], CAP);
  const float4* st4 = reinterpret_cast<const float4*>(stext);
  const int* bkt = buckets + p * CAP;

  int row = -1, nrow;
  s16x4 r0, r1, nr0, nr1;
  if (wave < n) {
    row = bkt[wave];
    const s16x4* ib = reinterpret_cast<const s16x4*>(imgb + (size_t)row * DIM);
    r0 = ib[lane]; r1 = ib[64 + lane];
  }

  for (int i = wave; i < n; i += 4) {
    const int inext = i + 4;
    if (inext < n) {
      nrow = bkt[inext];
      const s16x4* ib = reinterpret_cast<const s16x4*>(imgb + (size_t)nrow * DIM);
      nr0 = ib[lane]; nr1 = ib[64 + lane];
    }

    const float ax0 = bf2f(r0[0]), ax1 = bf2f(r0[1]),
                ax2 = bf2f(r0[2]), ax3 = bf2f(r0[3]);
    const float ay0 = bf2f(r1[0]), ay1 = bf2f(r1[1]),
                ay2 = bf2f(r1[2]), ay3 = bf2f(r1[3]);

    float acc[KSEL];
#pragma unroll
    for (int j = 0; j < KSEL; ++j) {
      const float4 b0 = st4[j * 128 + lane];
      const float4 b1 = st4[j * 128 + 64 + lane];
      float s = 0.f;
      s = fmaf(ax0, b0.x, s); s = fmaf(ax1, b0.y, s);
      s = fmaf(ax2, b0.z, s); s = fmaf(ax3, b0.w, s);
      s = fmaf(ay0, b1.x, s); s = fmaf(ay1, b1.y, s);
      s = fmaf(ay2, b1.z, s); s = fmaf(ay3, b1.w, s);
      acc[j] = s;
    }
#pragma unroll
    for (int j = 0; j < KSEL; ++j) {
#pragma unroll
      for (int off = 32; off; off >>= 1)
        acc[j] += __shfl_xor(acc[j], off);
    }
    float v = acc[0];
#pragma unroll
    for (int j = 1; j < KSEL; ++j) if (lane == j) v = acc[j];
    if (lane < KSEL)
      out[(size_t)row * NCLASSES + p * KSEL + lane] = v * sfac[lane];

    row = nrow; r0 = nr0; r1 = nr1;
  }
}

// ---------------------------------------------------------------------------
extern "C" void kernel_launch(void* const* d_in, const int* in_sizes, int n_in,
                              void* d_out, int out_size, void* d_ws, size_t ws_size,
                              hipStream_t stream) {
  const float* img    = (const float*)d_in[0];
  const float* proto  = (const float*)d_in[1];
  const float* text   = (const float*)d_in[2];
  const float* lscale = (const float*)d_in[3];

  unsigned short* prob = (unsigned short*)d_out;
  f32x4*  outz = (f32x4*)((char*)d_out + PROB_BYTES);
  float*  out  = (float*)d_out;

  // ws layout (~5.05 MB): counts @0, buckets @4096, imgb @ 4096+1MB
  int*   counts  = (int*)d_ws;
  int*   buckets = (int*)((char*)d_ws + 4096);
  short* imgb    = (short*)((char*)d_ws + 4096 + 1048576);

  k_prep<<<1024, 256, 0, stream>>>(img, imgb, counts);
  k_gemm<<<dim3(B_ROWS / GBM, 1024 / GBN), 256, 0, stream>>>(
      imgb, proto, prob, outz);
  k_select<<<B_ROWS / 4, 256, 0, stream>>>(prob, img, proto, counts, buckets, outz);
  k_compute<<<NPROTO, 256, 0, stream>>>(imgb, text, counts, buckets, lscale, out);
}